// Round 2
// baseline (541.371 us; speedup 1.0000x reference)
//
#include <hip/hip_runtime.h>
#include <hip/hip_bf16.h>

#define N_NODES 8192
#define E_EDGES 524288
#define D_DIM   256
#define NEG_FILL -1e9f

#define PROJ_BLOCKS 256
#define ROWS_PER_BLOCK 32
#define FILL_BLOCKS 2048

typedef float vfloat4 __attribute__((ext_vector_type(4)));

__device__ __forceinline__ float bf2f(unsigned short u) {
    union { unsigned int i; float f; } v;
    v.i = ((unsigned int)u) << 16;
    return v.f;
}

// Fused kernel: blocks [0, PROJ_BLOCKS) compute A = h@W1[0:256], B = h@W1[256:512]
// (stored as bf16 into ws); remaining blocks fill out with -1e9.
__global__ __launch_bounds__(256) void fill_proj_kernel(
    const float* __restrict__ h,
    const float* __restrict__ W1,
    float* __restrict__ out,
    unsigned short* __restrict__ AB)   // A at [0, N*D), B at [N*D, 2*N*D)
{
    if (blockIdx.x < PROJ_BLOCKS) {
        __shared__ float hs[ROWS_PER_BLOCK * D_DIM];   // 32 KB
        const int t  = threadIdx.x;
        const int r0 = blockIdx.x * ROWS_PER_BLOCK;
        const float* hp = h + (long long)r0 * D_DIM;
        for (int i = t; i < ROWS_PER_BLOCK * D_DIM; i += 256) hs[i] = hp[i];
        __syncthreads();

        float accA[ROWS_PER_BLOCK];
        float accB[ROWS_PER_BLOCK];
        #pragma unroll
        for (int r = 0; r < ROWS_PER_BLOCK; ++r) { accA[r] = 0.f; accB[r] = 0.f; }

        for (int k = 0; k < D_DIM; k += 4) {
            float wa0 = W1[(k + 0) * D_DIM + t];
            float wa1 = W1[(k + 1) * D_DIM + t];
            float wa2 = W1[(k + 2) * D_DIM + t];
            float wa3 = W1[(k + 3) * D_DIM + t];
            float wb0 = W1[(256 + k + 0) * D_DIM + t];
            float wb1 = W1[(256 + k + 1) * D_DIM + t];
            float wb2 = W1[(256 + k + 2) * D_DIM + t];
            float wb3 = W1[(256 + k + 3) * D_DIM + t];
            #pragma unroll
            for (int r = 0; r < ROWS_PER_BLOCK; ++r) {
                const float4 hv = *(const float4*)&hs[r * D_DIM + k];
                accA[r] = fmaf(hv.x, wa0, accA[r]);
                accA[r] = fmaf(hv.y, wa1, accA[r]);
                accA[r] = fmaf(hv.z, wa2, accA[r]);
                accA[r] = fmaf(hv.w, wa3, accA[r]);
                accB[r] = fmaf(hv.x, wb0, accB[r]);
                accB[r] = fmaf(hv.y, wb1, accB[r]);
                accB[r] = fmaf(hv.z, wb2, accB[r]);
                accB[r] = fmaf(hv.w, wb3, accB[r]);
            }
        }

        unsigned short* A = AB;
        unsigned short* B = AB + (long long)N_NODES * D_DIM;
        #pragma unroll
        for (int r = 0; r < ROWS_PER_BLOCK; ++r) {
            union { float f; unsigned int i; } va, vb;
            va.f = accA[r]; vb.f = accB[r];
            // round-to-nearest-even bf16 (RN with rounding bit)
            unsigned int ra = (va.i + 0x7FFF + ((va.i >> 16) & 1)) >> 16;
            unsigned int rb = (vb.i + 0x7FFF + ((vb.i >> 16) & 1)) >> 16;
            A[(long long)(r0 + r) * D_DIM + t] = (unsigned short)ra;
            B[(long long)(r0 + r) * D_DIM + t] = (unsigned short)rb;
        }
    } else {
        // fill out with -1e9 using nontemporal vector stores
        const int b  = blockIdx.x - PROJ_BLOCKS;
        const int nb = gridDim.x - PROJ_BLOCKS;
        const int nvec = (N_NODES / 4) * N_NODES;   // 16777216
        vfloat4 fv = { NEG_FILL, NEG_FILL, NEG_FILL, NEG_FILL };
        vfloat4* o4 = (vfloat4*)out;
        for (int i = b * 256 + threadIdx.x; i < nvec; i += nb * 256)
            __builtin_nontemporal_store(fv, &o4[i]);
    }
}

// One wave (64 lanes) per edge: each lane handles 4 of the 256 hidden dims.
__global__ __launch_bounds__(256) void edge_kernel(
    const int* __restrict__ eidx,
    const float* __restrict__ eattr,
    const float* __restrict__ W1,
    const float* __restrict__ W2,
    const unsigned short* __restrict__ AB,
    float* __restrict__ out)
{
    const int wave = blockIdx.x * 4 + (threadIdx.x >> 6);
    const int lane = threadIdx.x & 63;
    if (wave >= E_EDGES) return;

    const int   l    = eidx[wave];
    const int   r    = eidx[E_EDGES + wave];
    const float attr = eattr[wave];

    const int j0 = lane * 4;
    const unsigned short* Arow = AB + (long long)l * D_DIM + j0;
    const unsigned short* Brow = AB + (long long)N_NODES * D_DIM + (long long)r * D_DIM + j0;
    const ushort4 a4 = *(const ushort4*)Arow;
    const ushort4 b4 = *(const ushort4*)Brow;
    const float4  wl = *(const float4*)&W1[512 * D_DIM + j0];
    const float4  w2 = *(const float4*)&W2[j0];

    float s = 0.f;
    {
        float hv;
        hv = fmaf(attr, wl.x, bf2f(a4.x) + bf2f(b4.x)); hv = fmaxf(hv, 0.f); s = fmaf(hv, w2.x, s);
        hv = fmaf(attr, wl.y, bf2f(a4.y) + bf2f(b4.y)); hv = fmaxf(hv, 0.f); s = fmaf(hv, w2.y, s);
        hv = fmaf(attr, wl.z, bf2f(a4.z) + bf2f(b4.z)); hv = fmaxf(hv, 0.f); s = fmaf(hv, w2.z, s);
        hv = fmaf(attr, wl.w, bf2f(a4.w) + bf2f(b4.w)); hv = fmaxf(hv, 0.f); s = fmaf(hv, w2.w, s);
    }
    // 64-lane butterfly reduction
    #pragma unroll
    for (int off = 32; off > 0; off >>= 1)
        s += __shfl_xor(s, off, 64);

    if (lane == 0)
        out[(long long)l * N_NODES + r] = s;
}

extern "C" void kernel_launch(void* const* d_in, const int* in_sizes, int n_in,
                              void* d_out, int out_size, void* d_ws, size_t ws_size,
                              hipStream_t stream) {
    // inputs: 0=encoded (unused), 1=h, 2=edge_index, 3=edge_attr, 4=W1, 5=W2
    const float* h     = (const float*)d_in[1];
    const int*   eidx  = (const int*)d_in[2];
    const float* eattr = (const float*)d_in[3];
    const float* W1    = (const float*)d_in[4];
    const float* W2    = (const float*)d_in[5];
    float* out = (float*)d_out;
    unsigned short* AB = (unsigned short*)d_ws;   // 8 MiB (2 * N * D bf16)

    fill_proj_kernel<<<PROJ_BLOCKS + FILL_BLOCKS, 256, 0, stream>>>(h, W1, out, AB);
    edge_kernel<<<E_EDGES / 4, 256, 0, stream>>>(eidx, eattr, W1, W2, AB, out);
}